// Round 3
// baseline (163.602 us; speedup 1.0000x reference)
//
#include <hip/hip_runtime.h>

// HydrophobicPairs: E[b,l] = h[seq[b,l]] * sum_k h[seq[b, j_idx[b,l,k]]] * g(r[b,l,k])
// g(r) = exp(-(min(r,md)-r_peak)^2 / (2 sigma^2)) * (r < md - 1e-4)
// B=32, L=8192, K=64, NUM_AA=20.
//
// R3: two-kernel design.
//  K1: h_all[b,l] = h[seq[b,l]]  (1 MB in d_ws) — removes all gathers from staging.
//  K2: 512-thr blocks (4/CU, 32KB LDS each -> 32 waves/CU), stage h_all row via
//      coalesced copy, 16 lanes/row fully-coalesced 1KB load insts, software-
//      pipelined (iter0 loads before the barrier). R2 was latency-bound:
//      occupancy 56%, VALU 20%, HBM 20%.

#define BB 32
#define LL 8192
#define KK 64
#define TPB 512
#define RPB 256   // rows per block

__global__ __launch_bounds__(256) void _hp_hall_kernel(
    const int* __restrict__ seq, const float* __restrict__ h,
    float* __restrict__ h_all)
{
    const int idx = blockIdx.x * 256 + threadIdx.x;      // int4 index, 65536 total
    const int4 s = ((const int4*)seq)[idx];
    ((float4*)h_all)[idx] = make_float4(h[s.x], h[s.y], h[s.z], h[s.w]);
}

__global__ __launch_bounds__(TPB) void _HydrophobicPairs_58256936403302_kernel(
    const float* __restrict__ r,          // [B,L,K]
    const int*   __restrict__ j_idx,      // [B,L,K]
    const float* __restrict__ h_all,      // [B,L] precomputed h[seq]
    const float* __restrict__ r_half_raw, // [1]
    const float* __restrict__ tau_hp_raw, // [1]
    const int*   __restrict__ max_dist,   // [1]
    float*       __restrict__ out)        // [B,L]
{
    __shared__ float h_row[LL];           // 32 KB
    const int tid   = threadIdx.x;
    const int b     = blockIdx.x >> 5;    // 32 chunks per b
    const int chunk = blockIdx.x & 31;
    const int lbase = chunk * RPB;

    // Stage h_all[b, :] -> LDS (pure coalesced copy, no gather).
    const float4* hsrc = (const float4*)(h_all + b * LL);
    #pragma unroll
    for (int i = 0; i < 4; ++i) {
        const int e4 = i * TPB + tid;     // 0..2047 float4s
        ((float4*)h_row)[e4] = hsrc[e4];
    }

    // Runtime scalars (broadcast, cached).
    const float md     = (float)max_dist[0];
    const float r_peak = log1pf(expf(r_half_raw[0]));            // softplus
    const float sigma  = log1pf(expf(tau_hp_raw[0])) + 0.1f;
    const float nscale = -1.44269504f / (2.0f * sigma * sigma);  // exp2 fold
    const float vthr   = md - 1e-4f;

    // 16 lanes/row: each global_load_dwordx4 covers a contiguous 1 KB segment.
    const int lane = tid & 15;
    const int rgrp = tid >> 4;            // 0..31 rows per iteration
    const long base0 = ((long)(b * LL + lbase + rgrp)) * KK + lane * 4;

    // Prefetch iter 0 before the barrier (global loads don't depend on LDS).
    float4 rv = *(const float4*)(r + base0);
    int4   jv = *(const int4*)(j_idx + base0);

    __syncthreads();

    #pragma unroll
    for (int it = 0; it < 8; ++it) {
        const float4 rc = rv;
        const int4   jc = jv;
        if (it < 7) {                     // software pipeline: next iter's loads
            const long nb = base0 + (long)(it + 1) * (32 * KK);
            rv = *(const float4*)(r + nb);
            jv = *(const int4*)(j_idx + nb);
        }

        float acc = 0.0f;
        #pragma unroll
        for (int u = 0; u < 4; ++u) {
            const float rvv = (&rc.x)[u];
            const unsigned j = (unsigned)(&jc.x)[u] & (LL - 1);
            const float hj = h_row[j];                    // LDS gather
            const float d  = fminf(rvv, md) - r_peak;
            float g = exp2f(d * d * nscale);              // v_exp_f32
            g = (rvv < vthr) ? g : 0.0f;
            acc = fmaf(hj, g, acc);
        }

        // Reduce across the 16-lane row group.
        acc += __shfl_xor(acc, 1);
        acc += __shfl_xor(acc, 2);
        acc += __shfl_xor(acc, 4);
        acc += __shfl_xor(acc, 8);

        if (lane == 0) {
            const int l_loc = lbase + it * 32 + rgrp;
            out[b * LL + l_loc] = h_row[l_loc] * acc;
        }
    }
}

extern "C" void kernel_launch(void* const* d_in, const int* in_sizes, int n_in,
                              void* d_out, int out_size, void* d_ws, size_t ws_size,
                              hipStream_t stream) {
    const int*   seq        = (const int*)d_in[0];
    const float* r          = (const float*)d_in[1];
    const int*   j_idx      = (const int*)d_in[2];
    const float* h          = (const float*)d_in[3];
    const float* r_half_raw = (const float*)d_in[4];
    const float* tau_hp_raw = (const float*)d_in[5];
    const int*   max_dist   = (const int*)d_in[6];
    float*       out        = (float*)d_out;
    float*       h_all      = (float*)d_ws;              // 1 MB scratch

    // K1: h_all[b,l] = h[seq[b,l]]  (65536 int4 elems)
    _hp_hall_kernel<<<dim3(256), dim3(256), 0, stream>>>(seq, h, h_all);

    // K2: main. 1024 blocks x 512 threads, 4 blocks/CU.
    _HydrophobicPairs_58256936403302_kernel<<<dim3(BB * (LL / RPB)), dim3(TPB), 0, stream>>>(
        r, j_idx, h_all, r_half_raw, tau_hp_raw, max_dist, out);
}

// Round 4
// 160.053 us; speedup vs baseline: 1.0222x; 1.0222x over previous
//
#include <hip/hip_runtime.h>

// HydrophobicPairs: E[b,l] = h[seq[b,l]] * sum_k h[seq[b, j_idx[b,l,k]]] * g(r[b,l,k])
// g(r) = exp(-(r_c - r_peak)^2 / (2 sigma^2)) * (r < md - 1e-4)
// B=32, L=8192, K=64, NUM_AA=20.
//
// R4: R3 was latency-bound (VALU 22%, HBM 18%, occ 58% — no pipe >25%).
//  - depth-2 software pipeline on the r/j_idx stream (latency tolerance
//    ~1200 cyc > 900 cyc HBM miss latency)
//  - fminf dropped (masked lanes make it redundant), Gaussian folded to
//    2 FMA + v_exp_f32.
// K1 precomputes h_all[b,l] = h[seq[b,l]] (1 MB in d_ws); K2 stages the
// 32 KB b-row into LDS with a pure coalesced copy and gathers via ds_read_b32.

#define BB 32
#define LL 8192
#define KK 64
#define TPB 512
#define RPB 256   // rows per block
#define DEPTH 2   // prefetch depth (iterations in flight)

__global__ __launch_bounds__(256) void _hp_hall_kernel(
    const int* __restrict__ seq, const float* __restrict__ h,
    float* __restrict__ h_all)
{
    const int idx = blockIdx.x * 256 + threadIdx.x;      // int4 index, 65536 total
    const int4 s = ((const int4*)seq)[idx];
    ((float4*)h_all)[idx] = make_float4(h[s.x], h[s.y], h[s.z], h[s.w]);
}

__global__ __launch_bounds__(TPB) void _HydrophobicPairs_58256936403302_kernel(
    const float* __restrict__ r,          // [B,L,K]
    const int*   __restrict__ j_idx,      // [B,L,K]
    const float* __restrict__ h_all,      // [B,L] precomputed h[seq]
    const float* __restrict__ r_half_raw, // [1]
    const float* __restrict__ tau_hp_raw, // [1]
    const int*   __restrict__ max_dist,   // [1]
    float*       __restrict__ out)        // [B,L]
{
    __shared__ float h_row[LL];           // 32 KB
    const int tid   = threadIdx.x;
    const int b     = blockIdx.x >> 5;    // 32 chunks per b
    const int chunk = blockIdx.x & 31;
    const int lbase = chunk * RPB;

    // Stage h_all[b, :] -> LDS (pure coalesced copy, no gather).
    const float4* hsrc = (const float4*)(h_all + b * LL);
    #pragma unroll
    for (int i = 0; i < 4; ++i) {
        const int e4 = i * TPB + tid;     // 0..2047 float4s
        ((float4*)h_row)[e4] = hsrc[e4];
    }

    // Runtime scalars (broadcast, cached).
    const float md     = (float)max_dist[0];
    const float r_peak = log1pf(expf(r_half_raw[0]));            // softplus
    const float sigma  = log1pf(expf(tau_hp_raw[0])) + 0.1f;
    const float nscale = -1.44269504f / (2.0f * sigma * sigma);  // -log2e/(2s^2)
    const float c1     = -2.0f * nscale * r_peak;
    const float c0     = nscale * r_peak * r_peak;
    const float vthr   = md - 1e-4f;

    // 16 lanes/row: each global_load_dwordx4 covers a contiguous 1 KB segment.
    const int lane = tid & 15;
    const int rgrp = tid >> 4;            // 0..31 rows per iteration
    const long base0 = ((long)(b * LL + lbase + rgrp)) * KK + lane * 4;

    // Fill the pipeline (global loads don't depend on LDS -> before barrier).
    float4 rbuf[DEPTH]; int4 jbuf[DEPTH];
    #pragma unroll
    for (int p = 0; p < DEPTH; ++p) {
        const long nb = base0 + (long)p * (32 * KK);
        rbuf[p] = *(const float4*)(r + nb);
        jbuf[p] = *(const int4*)(j_idx + nb);
    }

    __syncthreads();

    #pragma unroll
    for (int it = 0; it < 8; ++it) {
        const int slot = it & (DEPTH - 1);
        const float4 rc = rbuf[slot];
        const int4   jc = jbuf[slot];
        if (it + DEPTH < 8) {             // refill this slot DEPTH iters ahead
            const long nb = base0 + (long)(it + DEPTH) * (32 * KK);
            rbuf[slot] = *(const float4*)(r + nb);
            jbuf[slot] = *(const int4*)(j_idx + nb);
        }

        float acc = 0.0f;
        #pragma unroll
        for (int u = 0; u < 4; ++u) {
            const float rv = (&rc.x)[u];
            const unsigned j = (unsigned)(&jc.x)[u] & (LL - 1);
            const float hj = h_row[j];                        // LDS gather
            // exp(-(rv-r_peak)^2/(2s^2)) as exp2(nscale*rv^2 + c1*rv + c0):
            const float uexp = fmaf(rv, fmaf(nscale, rv, c1), c0);
            float g = exp2f(uexp);                            // v_exp_f32
            g = (rv < vthr) ? g : 0.0f;                       // validity mask
            acc = fmaf(hj, g, acc);
        }

        // Reduce across the 16-lane row group.
        acc += __shfl_xor(acc, 1);
        acc += __shfl_xor(acc, 2);
        acc += __shfl_xor(acc, 4);
        acc += __shfl_xor(acc, 8);

        if (lane == 0) {
            const int l_loc = lbase + it * 32 + rgrp;
            out[b * LL + l_loc] = h_row[l_loc] * acc;
        }
    }
}

extern "C" void kernel_launch(void* const* d_in, const int* in_sizes, int n_in,
                              void* d_out, int out_size, void* d_ws, size_t ws_size,
                              hipStream_t stream) {
    const int*   seq        = (const int*)d_in[0];
    const float* r          = (const float*)d_in[1];
    const int*   j_idx      = (const int*)d_in[2];
    const float* h          = (const float*)d_in[3];
    const float* r_half_raw = (const float*)d_in[4];
    const float* tau_hp_raw = (const float*)d_in[5];
    const int*   max_dist   = (const int*)d_in[6];
    float*       out        = (float*)d_out;
    float*       h_all      = (float*)d_ws;              // 1 MB scratch

    // K1: h_all[b,l] = h[seq[b,l]]  (65536 int4 elems)
    _hp_hall_kernel<<<dim3(256), dim3(256), 0, stream>>>(seq, h, h_all);

    // K2: main. 1024 blocks x 512 threads, 4 blocks/CU.
    _HydrophobicPairs_58256936403302_kernel<<<dim3(BB * (LL / RPB)), dim3(TPB), 0, stream>>>(
        r, j_idx, h_all, r_half_raw, tau_hp_raw, max_dist, out);
}